// Round 5
// baseline (250.451 us; speedup 1.0000x reference)
//
#include <hip/hip_runtime.h>
#include <hip/hip_bf16.h>
#include <math.h>

#define NN4   4096

typedef __attribute__((ext_vector_type(8))) short short8;
typedef __attribute__((ext_vector_type(8))) unsigned short ushort8;
typedef __attribute__((ext_vector_type(4))) unsigned short ushort4v;
typedef __attribute__((ext_vector_type(4))) float f32x4;

__device__ __forceinline__ unsigned short f2b(float f) {
  union { __hip_bfloat16 h; unsigned short u; } v;
  v.h = __float2bfloat16(f);
  return v.u;
}
__device__ __forceinline__ float b2f(unsigned short s) {
  return __uint_as_float(((unsigned int)s) << 16);
}
__device__ __forceinline__ ushort8 cvt8(f32x4 a, f32x4 b) {
  return (ushort8){f2b(a[0]), f2b(a[1]), f2b(a[2]), f2b(a[3]),
                   f2b(b[0]), f2b(b[1]), f2b(b[2]), f2b(b[3])};
}

#define GLOAD16(gp, lp) __builtin_amdgcn_global_load_lds( \
    (const __attribute__((address_space(1))) void*)(gp),  \
    (__attribute__((address_space(3))) void*)(lp), 16, 0, 0)

// ---------------- row normalize (mean/std over 512, ddof=1) -> bf16 ----------------
__global__ __launch_bounds__(256) void k_norm(const float* __restrict__ x,
                                              unsigned short* __restrict__ y) {
  int row  = blockIdx.x * 4 + (threadIdx.x >> 6);
  int lane = threadIdx.x & 63;
  const float4* src = (const float4*)(x + (size_t)row * 512);
  float4 a = src[lane];
  float4 b = src[lane + 64];
  float s = a.x + a.y + a.z + a.w + b.x + b.y + b.z + b.w;
#pragma unroll
  for (int off = 32; off; off >>= 1) s += __shfl_xor(s, off);
  float mean = s * (1.0f / 512.0f);
  float ssq = 0.f, d;
  d = a.x - mean; ssq += d * d;  d = a.y - mean; ssq += d * d;
  d = a.z - mean; ssq += d * d;  d = a.w - mean; ssq += d * d;
  d = b.x - mean; ssq += d * d;  d = b.y - mean; ssq += d * d;
  d = b.z - mean; ssq += d * d;  d = b.w - mean; ssq += d * d;
#pragma unroll
  for (int off = 32; off; off >>= 1) ssq += __shfl_xor(ssq, off);
  float inv = 1.0f / (sqrtf(ssq * (1.0f / 511.0f)) + 1e-9f);
  unsigned short* dst = y + (size_t)row * 512;
  ushort4v va = (ushort4v){f2b((a.x - mean) * inv), f2b((a.y - mean) * inv),
                           f2b((a.z - mean) * inv), f2b((a.w - mean) * inv)};
  ushort4v vb = (ushort4v){f2b((b.x - mean) * inv), f2b((b.y - mean) * inv),
                           f2b((b.z - mean) * inv), f2b((b.w - mean) * inv)};
  *(ushort4v*)(dst + lane * 4)       = va;
  *(ushort4v*)(dst + 256 + lane * 4) = vb;
}

// ------------------- MFMA GEMM: C[M,N] = A[M,K] @ B[N,K]^T -------------------
// EPI: 1 = bf16 store, 2 = bf16 store row-remapped r -> r + 4*(r>>6)  (V^T build)
#define LDSP 40
template<int AF32, int BF32, int EPI>
__global__ __launch_bounds__(256) void k_mfma(
    const void* __restrict__ Ap, int lda,
    const void* __restrict__ Bp, int ldb,
    void* __restrict__ Cp, int ldc,
    int M, int N, int K) {
  __shared__ unsigned short As[128 * LDSP];
  __shared__ unsigned short Bs[128 * LDSP];
  const int tid = threadIdx.x;
  const int m0 = blockIdx.x * 128, n0 = blockIdx.y * 128;
  const int lane = tid & 63, wid = tid >> 6;
  const int wr = (wid >> 1) << 6, wc = (wid & 1) << 6;
  const int srow = tid >> 1, sk = (tid & 1) << 4;
  f32x4 acc[4][4];
#pragma unroll
  for (int i = 0; i < 4; ++i)
#pragma unroll
    for (int j = 0; j < 4; ++j) acc[i][j] = (f32x4){0.f, 0.f, 0.f, 0.f};

  for (int k0 = 0; k0 < K; k0 += 32) {
    ushort8 va0, va1, vb0, vb1;
    {
      int gr = m0 + srow;
      if (gr < M) {
        if constexpr (AF32) {
          const float* s = (const float*)Ap + (size_t)gr * lda + k0 + sk;
          f32x4 f0 = *(const f32x4*)(s);
          f32x4 f1 = *(const f32x4*)(s + 4);
          f32x4 f2 = *(const f32x4*)(s + 8);
          f32x4 f3 = *(const f32x4*)(s + 12);
          va0 = cvt8(f0, f1); va1 = cvt8(f2, f3);
        } else {
          const unsigned short* s = (const unsigned short*)Ap + (size_t)gr * lda + k0 + sk;
          va0 = *(const ushort8*)(s);
          va1 = *(const ushort8*)(s + 8);
        }
      } else { va0 = (ushort8)0; va1 = (ushort8)0; }
    }
    {
      int gr = n0 + srow;
      if (gr < N) {
        if constexpr (BF32) {
          const float* s = (const float*)Bp + (size_t)gr * ldb + k0 + sk;
          f32x4 f0 = *(const f32x4*)(s);
          f32x4 f1 = *(const f32x4*)(s + 4);
          f32x4 f2 = *(const f32x4*)(s + 8);
          f32x4 f3 = *(const f32x4*)(s + 12);
          vb0 = cvt8(f0, f1); vb1 = cvt8(f2, f3);
        } else {
          const unsigned short* s = (const unsigned short*)Bp + (size_t)gr * ldb + k0 + sk;
          vb0 = *(const ushort8*)(s);
          vb1 = *(const ushort8*)(s + 8);
        }
      } else { vb0 = (ushort8)0; vb1 = (ushort8)0; }
    }
    __syncthreads();
    *(ushort8*)&As[srow * LDSP + sk]     = va0;
    *(ushort8*)&As[srow * LDSP + sk + 8] = va1;
    *(ushort8*)&Bs[srow * LDSP + sk]     = vb0;
    *(ushort8*)&Bs[srow * LDSP + sk + 8] = vb1;
    __syncthreads();
    short8 af[4], bf[4];
#pragma unroll
    for (int i = 0; i < 4; ++i)
      af[i] = *(const short8*)&As[(wr + (i << 4) + (lane & 15)) * LDSP + ((lane >> 4) << 3)];
#pragma unroll
    for (int j = 0; j < 4; ++j)
      bf[j] = *(const short8*)&Bs[(wc + (j << 4) + (lane & 15)) * LDSP + ((lane >> 4) << 3)];
#pragma unroll
    for (int i = 0; i < 4; ++i)
#pragma unroll
      for (int j = 0; j < 4; ++j)
        acc[i][j] = __builtin_amdgcn_mfma_f32_16x16x32_bf16(af[i], bf[j], acc[i][j], 0, 0, 0);
  }

#pragma unroll
  for (int i = 0; i < 4; ++i) {
#pragma unroll
    for (int j = 0; j < 4; ++j) {
#pragma unroll
      for (int reg = 0; reg < 4; ++reg) {
        int r = m0 + wr + (i << 4) + ((lane >> 4) << 2) + reg;
        int c = n0 + wc + (j << 4) + (lane & 15);
        if (r < M && c < N) {
          float v = acc[i][j][reg];
          if constexpr (EPI == 1) {
            ((unsigned short*)Cp)[(size_t)r * ldc + c] = f2b(v);
          } else {
            int r2 = r + ((r >> 6) << 2);
            ((unsigned short*)Cp)[(size_t)r2 * ldc + c] = f2b(v);
          }
        }
      }
    }
  }
}

// ---------- merged Q/K projection: grid.y low half -> (Bq,Cq), high half -> (Bk,Ck) ----------
__global__ __launch_bounds__(256) void k_proj2(
    const unsigned short* __restrict__ Ap, int lda,
    const float* __restrict__ Bq, const float* __restrict__ Bk, int ldb,
    unsigned short* __restrict__ Cq, unsigned short* __restrict__ Ck, int ldc,
    int M, int N, int K) {
  __shared__ unsigned short As[128 * LDSP];
  __shared__ unsigned short Bs[128 * LDSP];
  const int tid = threadIdx.x;
  const int half = gridDim.y >> 1;
  const int isK = blockIdx.y >= half;
  const float* Bp = isK ? Bk : Bq;
  unsigned short* Cp = isK ? Ck : Cq;
  const int m0 = blockIdx.x * 128, n0 = (isK ? blockIdx.y - half : blockIdx.y) * 128;
  const int lane = tid & 63, wid = tid >> 6;
  const int wr = (wid >> 1) << 6, wc = (wid & 1) << 6;
  const int srow = tid >> 1, sk = (tid & 1) << 4;
  f32x4 acc[4][4];
#pragma unroll
  for (int i = 0; i < 4; ++i)
#pragma unroll
    for (int j = 0; j < 4; ++j) acc[i][j] = (f32x4){0.f, 0.f, 0.f, 0.f};

  for (int k0 = 0; k0 < K; k0 += 32) {
    ushort8 va0, va1, vb0, vb1;
    {
      const unsigned short* s = Ap + (size_t)(m0 + srow) * lda + k0 + sk;
      va0 = *(const ushort8*)(s);
      va1 = *(const ushort8*)(s + 8);
    }
    {
      int gr = n0 + srow;
      if (gr < N) {
        const float* s = Bp + (size_t)gr * ldb + k0 + sk;
        f32x4 f0 = *(const f32x4*)(s);
        f32x4 f1 = *(const f32x4*)(s + 4);
        f32x4 f2 = *(const f32x4*)(s + 8);
        f32x4 f3 = *(const f32x4*)(s + 12);
        vb0 = cvt8(f0, f1); vb1 = cvt8(f2, f3);
      } else { vb0 = (ushort8)0; vb1 = (ushort8)0; }
    }
    __syncthreads();
    *(ushort8*)&As[srow * LDSP + sk]     = va0;
    *(ushort8*)&As[srow * LDSP + sk + 8] = va1;
    *(ushort8*)&Bs[srow * LDSP + sk]     = vb0;
    *(ushort8*)&Bs[srow * LDSP + sk + 8] = vb1;
    __syncthreads();
    short8 af[4], bf[4];
#pragma unroll
    for (int i = 0; i < 4; ++i)
      af[i] = *(const short8*)&As[(wr + (i << 4) + (lane & 15)) * LDSP + ((lane >> 4) << 3)];
#pragma unroll
    for (int j = 0; j < 4; ++j)
      bf[j] = *(const short8*)&Bs[(wc + (j << 4) + (lane & 15)) * LDSP + ((lane >> 4) << 3)];
#pragma unroll
    for (int i = 0; i < 4; ++i)
#pragma unroll
      for (int j = 0; j < 4; ++j)
        acc[i][j] = __builtin_amdgcn_mfma_f32_16x16x32_bf16(af[i], bf[j], acc[i][j], 0, 0, 0);
  }
#pragma unroll
  for (int i = 0; i < 4; ++i)
#pragma unroll
    for (int j = 0; j < 4; ++j)
#pragma unroll
      for (int reg = 0; reg < 4; ++reg) {
        int r = m0 + wr + (i << 4) + ((lane >> 4) << 2) + reg;
        int c = n0 + wc + (j << 4) + (lane & 15);
        if (c < N) Cp[(size_t)r * ldc + c] = f2b(acc[i][j][reg]);
      }
}

// --------- CVX split-K: Pb[z][4096][NF*16] (bf16) = cnt-slice @ Bt^T ---------
// 2-phase pipeline: A (f32->bf16) reg-staged load-early/write-late; B via
// global_load_lds with source-side XOR swizzle (byte ^= (byte>>3)&0x30).
template<int NF>
__global__ __launch_bounds__(256, 2) void k_cvxg(
    const float* __restrict__ cnt,
    const unsigned short* __restrict__ Bt,     // [NF*16][4096] bf16 (V^T + ones/zero rows)
    unsigned short* __restrict__ Pb) {
  constexpr int LDB = NF * 16;
  __shared__ unsigned short As[2][128 * 40];
  __shared__ unsigned short Bs[2][LDB * 32];
  const int tid = threadIdx.x, lane = tid & 63, wid = tid >> 6;
  const int hi = lane >> 4, lo = lane & 15;
  const int m0 = blockIdx.x * 128;
  const int kbeg = blockIdx.y * 512, kend = kbeg + 512;
  const int arow = tid >> 1, ak = (tid & 1) << 4;
  const int boff = (lo * 64 + hi * 16) ^ (((lo >> 1) & 3) << 4);  // swizzled read offset

  f32x4 acc[2][NF];
#pragma unroll
  for (int i = 0; i < 2; ++i)
#pragma unroll
    for (int j = 0; j < NF; ++j) acc[i][j] = (f32x4){0.f, 0.f, 0.f, 0.f};

  f32x4 ar0, ar1, ar2, ar3;
  // prologue: stage k = kbeg into buf 0
  {
    const float* s = cnt + (size_t)(m0 + arow) * 4096 + kbeg + ak;
    ar0 = *(const f32x4*)(s);     ar1 = *(const f32x4*)(s + 4);
    ar2 = *(const f32x4*)(s + 8); ar3 = *(const f32x4*)(s + 12);
  }
  for (int c = wid; c < NF; c += 4) {
    int P = c * 1024 + lane * 16;
    int L = P ^ ((P >> 3) & 0x30);
    GLOAD16(Bt + (size_t)(L >> 6) * 4096 + kbeg + ((L & 63) >> 1),
            (char*)&Bs[0][0] + c * 1024);
  }
  *(ushort8*)&As[0][arow * 40 + ak]     = cvt8(ar0, ar1);
  *(ushort8*)&As[0][arow * 40 + ak + 8] = cvt8(ar2, ar3);
  asm volatile("s_waitcnt vmcnt(0)" ::: "memory");
  __syncthreads();

  for (int k0 = kbeg; k0 < kend; k0 += 32) {
    const int cur = ((k0 - kbeg) >> 5) & 1, nxt = cur ^ 1;
    const bool more = (k0 + 32 < kend);
    if (more) {
      const float* s = cnt + (size_t)(m0 + arow) * 4096 + (k0 + 32) + ak;
      ar0 = *(const f32x4*)(s);     ar1 = *(const f32x4*)(s + 4);
      ar2 = *(const f32x4*)(s + 8); ar3 = *(const f32x4*)(s + 12);
      for (int c = wid; c < NF; c += 4) {
        int P = c * 1024 + lane * 16;
        int L = P ^ ((P >> 3) & 0x30);
        GLOAD16(Bt + (size_t)(L >> 6) * 4096 + (k0 + 32) + ((L & 63) >> 1),
                (char*)&Bs[nxt][0] + c * 1024);
      }
    }
    short8 af0 = *(const short8*)&As[cur][(32 * wid + lo) * 40 + hi * 8];
    short8 af1 = *(const short8*)&As[cur][(32 * wid + 16 + lo) * 40 + hi * 8];
#pragma unroll
    for (int j = 0; j < NF; ++j) {
      short8 bf = *(const short8*)((const char*)&Bs[cur][0] + j * 1024 + boff);
      acc[0][j] = __builtin_amdgcn_mfma_f32_16x16x32_bf16(af0, bf, acc[0][j], 0, 0, 0);
      acc[1][j] = __builtin_amdgcn_mfma_f32_16x16x32_bf16(af1, bf, acc[1][j], 0, 0, 0);
    }
    if (more) {
      *(ushort8*)&As[nxt][arow * 40 + ak]     = cvt8(ar0, ar1);
      *(ushort8*)&As[nxt][arow * 40 + ak + 8] = cvt8(ar2, ar3);
    }
    asm volatile("s_waitcnt vmcnt(0)" ::: "memory");
    __syncthreads();
  }
  unsigned short* P = Pb + (size_t)blockIdx.y * 4096 * LDB;
#pragma unroll
  for (int i = 0; i < 2; ++i)
#pragma unroll
    for (int j = 0; j < NF; ++j)
#pragma unroll
      for (int reg = 0; reg < 4; ++reg) {
        int r = m0 + 32 * wid + 16 * i + 4 * hi + reg;
        P[(size_t)r * LDB + 16 * j + lo] = f2b(acc[i][j][reg]);
      }
}

// ---------- reduce bf16 split-K partials + transpose -> bf16 [orow][4096] ----------
__global__ __launch_bounds__(256) void k_tredB(const unsigned short* __restrict__ in, int ld,
                                               int nsl, unsigned short* __restrict__ out,
                                               int orow) {
  __shared__ float t[64][65];
  int n0 = blockIdx.x << 6, d0 = blockIdx.y << 6;
  int c = threadIdx.x & 63, r4 = threadIdx.x >> 6;
  size_t pstride = (size_t)4096 * ld;
#pragma unroll
  for (int i = 0; i < 16; ++i) {
    int r = r4 + (i << 2);
    float s = 0.f;
    if (d0 + c < ld)
      for (int z = 0; z < nsl; ++z)
        s += b2f(in[z * pstride + (size_t)(n0 + r) * ld + d0 + c]);
    t[c][r] = s;
  }
  __syncthreads();
#pragma unroll
  for (int i = 0; i < 16; ++i) {
    int r = r4 + (i << 2);
    if (d0 + r < orow)
      out[(size_t)(d0 + r) * 4096 + n0 + c] = f2b(t[r][c]);
  }
}

// ---------------- fused GKAT attention: num = exp(Q K^T / 8) @ CVX^T ----------------
__global__ __launch_bounds__(256, 2) void k_attn(
    const unsigned short* __restrict__ Qg, const unsigned short* __restrict__ Kg,
    int ldqk, const unsigned short* __restrict__ CVg,
    float* __restrict__ parts) {
  __shared__ unsigned short Ks[128 * 72];
  __shared__ unsigned short Cs[80 * 136];
  __shared__ unsigned short Es[128 * 136];
  const int tid = threadIdx.x, lane = tid & 63, wid = tid >> 6;
  const int hi = lane >> 4, lo = lane & 15;
  const int qb = blockIdx.x, h = blockIdx.y, sl = blockIdx.z;
  const int n0 = qb * 128;
  const int MS = 4096 / gridDim.z;
  const int m0beg = sl * MS;
  const int wr = (wid >> 1) << 6, wc = (wid & 1) << 6;

  short8 qf[4][2];
  const unsigned short* Qh = Qg + (size_t)h * 64;
#pragma unroll
  for (int j = 0; j < 4; ++j)
#pragma unroll
    for (int t = 0; t < 2; ++t)
      qf[j][t] = *(const short8*)(Qh + (size_t)(n0 + wc + 16 * j + lo) * ldqk + t * 32 + hi * 8);

  const unsigned short* CVh = CVg + (size_t)h * 68 * NN4;
  const unsigned short* Kh  = Kg + (size_t)h * 64;

  f32x4 accn[2][5];
#pragma unroll
  for (int i = 0; i < 2; ++i)
#pragma unroll
    for (int j = 0; j < 5; ++j) accn[i][j] = (f32x4){0.f, 0.f, 0.f, 0.f};

  for (int mt = 0; mt < MS; mt += 128) {
    const int m0 = m0beg + mt;
    __syncthreads();
    {
      const int row = tid >> 1, half = (tid & 1) << 5;
      const unsigned short* src = Kh + (size_t)(m0 + row) * ldqk + half;
      ushort8 v0 = *(const ushort8*)(src);
      ushort8 v1 = *(const ushort8*)(src + 8);
      ushort8 v2 = *(const ushort8*)(src + 16);
      ushort8 v3 = *(const ushort8*)(src + 24);
      unsigned short* dp = &Ks[row * 72 + half];
      *(ushort8*)(dp) = v0; *(ushort8*)(dp + 8) = v1;
      *(ushort8*)(dp + 16) = v2; *(ushort8*)(dp + 24) = v3;
    }
#pragma unroll
    for (int k = 0; k < 5; ++k) {
      int c = tid + k * 256;
      int row = c >> 4, col = (c & 15) << 3;
      ushort8 v = (ushort8)0;
      if (row < 68) v = *(const ushort8*)(CVh + (size_t)row * NN4 + m0 + col);
      *(ushort8*)&Cs[row * 136 + col] = v;
    }
    __syncthreads();
    f32x4 s[4][4];
#pragma unroll
    for (int i = 0; i < 4; ++i)
#pragma unroll
      for (int j = 0; j < 4; ++j) s[i][j] = (f32x4){0.f, 0.f, 0.f, 0.f};
    short8 kf[4][2];
#pragma unroll
    for (int i = 0; i < 4; ++i)
#pragma unroll
      for (int t = 0; t < 2; ++t)
        kf[i][t] = *(const short8*)&Ks[(wr + 16 * i + lo) * 72 + t * 32 + hi * 8];
#pragma unroll
    for (int t = 0; t < 2; ++t)
#pragma unroll
      for (int i = 0; i < 4; ++i)
#pragma unroll
        for (int j = 0; j < 4; ++j)
          s[i][j] = __builtin_amdgcn_mfma_f32_16x16x32_bf16(kf[i][t], qf[j][t], s[i][j], 0, 0, 0);
#pragma unroll
    for (int i = 0; i < 4; ++i)
#pragma unroll
      for (int j = 0; j < 4; ++j) {
        unsigned int u0 = (unsigned int)f2b(__expf(s[i][j][0] * 0.125f)) |
                          ((unsigned int)f2b(__expf(s[i][j][1] * 0.125f)) << 16);
        unsigned int u1 = (unsigned int)f2b(__expf(s[i][j][2] * 0.125f)) |
                          ((unsigned int)f2b(__expf(s[i][j][3] * 0.125f)) << 16);
        unsigned long long pk = (unsigned long long)u0 | ((unsigned long long)u1 << 32);
        *(unsigned long long*)&Es[(size_t)(wc + 16 * j + lo) * 136 + wr + 16 * i + 4 * hi] = pk;
      }
    __syncthreads();
#pragma unroll
    for (int t2 = 0; t2 < 4; ++t2) {
      short8 ea0 = *(const short8*)&Es[(32 * wid + lo) * 136 + t2 * 32 + hi * 8];
      short8 ea1 = *(const short8*)&Es[(32 * wid + 16 + lo) * 136 + t2 * 32 + hi * 8];
      short8 cb[5];
#pragma unroll
      for (int j2 = 0; j2 < 5; ++j2)
        cb[j2] = *(const short8*)&Cs[(16 * j2 + lo) * 136 + t2 * 32 + hi * 8];
#pragma unroll
      for (int j2 = 0; j2 < 5; ++j2) {
        accn[0][j2] = __builtin_amdgcn_mfma_f32_16x16x32_bf16(ea0, cb[j2], accn[0][j2], 0, 0, 0);
        accn[1][j2] = __builtin_amdgcn_mfma_f32_16x16x32_bf16(ea1, cb[j2], accn[1][j2], 0, 0, 0);
      }
    }
  }
  float* P = parts + (((size_t)h * gridDim.x + qb) * gridDim.z + sl) * (128 * 80);
#pragma unroll
  for (int i2 = 0; i2 < 2; ++i2)
#pragma unroll
    for (int j2 = 0; j2 < 5; ++j2)
#pragma unroll
      for (int reg = 0; reg < 4; ++reg) {
        int r = 32 * wid + 16 * i2 + 4 * hi + reg;
        int c = 16 * j2 + lo;
        P[(size_t)r * 80 + c] = accn[i2][j2][reg];
      }
}

// ---------- merge slices: x = num/(den+1e-9), elu, bf16 store ----------
__global__ void k_fin2(const float* __restrict__ parts, int nsl,
                       unsigned short* __restrict__ hb, int ldh) {
  int idx = blockIdx.x * 256 + threadIdx.x;
  int d = idx & 63, r = (idx >> 6) & 4095, h = idx >> 18;
  size_t b0 = ((size_t)(h * 32 + (r >> 7)) * nsl) * 10240 + (size_t)(r & 127) * 80;
  float nm = 0.f, dn = 0.f;
  for (int sl = 0; sl < nsl; ++sl) {
    const float* p = parts + b0 + (size_t)sl * 10240;
    nm += p[d]; dn += p[64];
  }
  float x = nm / (dn + 1e-9f);
  x = x > 0.f ? x : expm1f(x);
  hb[(size_t)r * ldh + h * 64 + d] = f2b(x);
}

// ---------- ones/zero rows: V1xT rows h*68+64+j ----------
__global__ void k_fix1(unsigned short* __restrict__ v) {
  int idx = blockIdx.x * 256 + threadIdx.x;   // 4096*16
  int n = idx & 4095, r16 = idx >> 12;
  int h = r16 >> 2, j = r16 & 3;
  v[(size_t)(h * 68 + 64 + j) * NN4 + n] = (j == 0) ? 0x3F80 : 0;
}
// ---------- V2xT rows 64..79: row 64 = ones, rest zero ----------
__global__ void k_fix2(unsigned short* __restrict__ v) {
  int idx = blockIdx.x * 256 + threadIdx.x;   // 4096*16
  int n = idx & 4095, j = idx >> 12;
  v[(size_t)(64 + j) * NN4 + n] = (j == 0) ? 0x3F80 : 0;
}

// ---------- classifier ----------
__global__ void k_cls(const unsigned short* __restrict__ h2, const float* __restrict__ Wc,
                      const float* __restrict__ bc, float* __restrict__ out) {
  int idx = blockIdx.x * 256 + threadIdx.x;
  int r = idx >> 4, cl = idx & 15;
  if (cl >= 10) return;
  float s = 0.f;
  for (int k = 0; k < 64; ++k) s += b2f(h2[(size_t)r * 64 + k]) * Wc[cl * 64 + k];
  out[(size_t)r * 10 + cl] = s + bc[cl];
}

extern "C" void kernel_launch(void* const* d_in, const int* in_sizes, int n_in,
                              void* d_out, int out_size, void* d_ws, size_t ws_size,
                              hipStream_t stream) {
  (void)in_sizes; (void)n_in; (void)out_size; (void)ws_size;
  const float* feats    = (const float*)d_in[0];
  const float* counting = (const float*)d_in[1];
  const float* Wq1 = (const float*)d_in[2];
  const float* Wk1 = (const float*)d_in[3];
  const float* Wv1 = (const float*)d_in[4];
  const float* Wq2 = (const float*)d_in[5];
  const float* Wk2 = (const float*)d_in[6];
  const float* Wv2 = (const float*)d_in[7];
  const float* Wc  = (const float*)d_in[8];
  const float* bc  = (const float*)d_in[9];
  float* out = (float*)d_out;

  char* w = (char*)d_ws;
  size_t off = 0;
  auto alloc = [&](size_t bytes) { void* p = w + off; off += (bytes + 255) & ~(size_t)255; return p; };
  unsigned short* hnb    = (unsigned short*)alloc((size_t)4096 * 512 * 2);
  unsigned short* Q1b    = (unsigned short*)alloc((size_t)4096 * 256 * 2);
  unsigned short* K1b    = (unsigned short*)alloc((size_t)4096 * 256 * 2);
  unsigned short* V1xT   = (unsigned short*)alloc((size_t)272 * 4096 * 2);
  unsigned short* CVX1Tb = (unsigned short*)alloc((size_t)272 * 4096 * 2);
  unsigned short* h1b    = (unsigned short*)alloc((size_t)4096 * 256 * 2);
  unsigned short* Q2b    = (unsigned short*)alloc((size_t)4096 * 64 * 2);
  unsigned short* K2b    = (unsigned short*)alloc((size_t)4096 * 64 * 2);
  unsigned short* V2xT   = (unsigned short*)alloc((size_t)80 * 4096 * 2);
  unsigned short* CVX2Tb = (unsigned short*)alloc((size_t)68 * 4096 * 2);
  unsigned short* h2b    = (unsigned short*)alloc((size_t)4096 * 64 * 2);
  void*           big    = alloc((size_t)21 * 1024 * 1024);   // cvx partials (17.8MB) / attn parts (21MB)

  k_norm<<<1024, 256, 0, stream>>>(feats, hnb);

  // layer-1 projections; V produced transposed w/ per-head ones-row slots
  k_proj2<<<dim3(32, 4), 256, 0, stream>>>(hnb, 512, Wq1, Wk1, 512, Q1b, K1b, 256, 4096, 256, 512);
  k_mfma<1, 0, 2><<<dim3(2, 32), 256, 0, stream>>>(Wv1, 512, hnb, 512, V1xT, 4096, 256, 4096, 512);
  k_fix1<<<256, 256, 0, stream>>>(V1xT);

  // CVX1 = counting @ [V1|1] : pipelined split-K, bf16 partials, reduce+transpose
  k_cvxg<17><<<dim3(32, 8), 256, 0, stream>>>(counting, V1xT, (unsigned short*)big);
  k_tredB<<<dim3(64, 5), 256, 0, stream>>>((unsigned short*)big, 272, 8, CVX1Tb, 272);

  // layer-1 fused attention + merge
  k_attn<<<dim3(32, 4, 4), 256, 0, stream>>>(Q1b, K1b, 256, CVX1Tb, (float*)big);
  k_fin2<<<4096, 256, 0, stream>>>((float*)big, 4, h1b, 256);

  // layer-2 projections
  k_proj2<<<dim3(32, 2), 256, 0, stream>>>(h1b, 256, Wq2, Wk2, 256, Q2b, K2b, 64, 4096, 64, 256);
  k_mfma<1, 0, 2><<<dim3(1, 32), 256, 0, stream>>>(Wv2, 256, h1b, 256, V2xT, 4096, 64, 4096, 256);
  k_fix2<<<256, 256, 0, stream>>>(V2xT);

  // CVX2
  k_cvxg<5><<<dim3(32, 8), 256, 0, stream>>>(counting, V2xT, (unsigned short*)big);
  k_tredB<<<dim3(64, 2), 256, 0, stream>>>((unsigned short*)big, 80, 8, CVX2Tb, 68);

  // layer-2 fused attention + merge
  k_attn<<<dim3(32, 1, 8), 256, 0, stream>>>(Q2b, K2b, 64, CVX2Tb, (float*)big);
  k_fin2<<<1024, 256, 0, stream>>>((float*)big, 8, h2b, 64);

  k_cls<<<256, 256, 0, stream>>>(h2b, Wc, bc, out);
}